// Round 3
// baseline (572.401 us; speedup 1.0000x reference)
//
#include <hip/hip_runtime.h>
#include <cstddef>

// ---------------------------------------------------------------------------
// Decagon pipeline, fp32, algebraically collapsed output layers.
// Key identity: hardshrink(v, 1e-6) == v to within 1e-6, so
//   out2[t] = hshrink( xd[t] @ oW1 @ W2s + oB1 @ W2s + oB2s )
//           = hshrink( PP'[a] + QQ[b] ),  PP' = fX@M2_hi + Cvec folded in.
//
// R1: bucketed edge aggregation (degree count -> scan -> fill -> block sum)
//     replacing 3.9M float atomicAdds. 765 -> 567 us.
// R2: split-K + LDS-staged W for the latency-bound layer-1 MLP; W staged in
//     LDS for sage/pq; pq merged; pE memcpy dropped. 567 -> 509 us.
// R3: k_final was gathering 600 MB from a 4 MB PPQQ table that cannot
//     co-reside with the 300 MB write stream in the 4 MB per-XCD L2 ->
//     HBM refetch. Bucket tpl by drug a: PP'[a] lives in registers per
//     block, QQ gathers hit a compact 2 MB L2-resident array. k_final2
//     should be write-bound (~50-65 us).
// ---------------------------------------------------------------------------

__device__ __forceinline__ float hshrink(float v) {
    return (fabsf(v) > 1e-6f) ? v : 0.0f;
}

// Layer-1 partial GEMM: Cp[sk][row][col] = A[row, sk*KS : (sk+1)*KS] @ W-chunk.
// 16 rows/block, W staged in LDS as 64x128 panels. grid (ceil(M/16), SK).
__global__ __launch_bounds__(256) void k_mlp1(const float* __restrict__ A,
                                              const float* __restrict__ W,
                                              float* __restrict__ Cp, int M, int K,
                                              int KS) {
    __shared__ float As[16 * 64];
    __shared__ float Ws[64 * 128];
    const int tid = threadIdx.x;
    const int r0  = blockIdx.x * 16;
    const int sk  = blockIdx.y;
    const int col = tid & 127;
    const int rh  = tid >> 7;  // 0/1 -> rows rh*8 .. rh*8+7
    float acc[8] = {};

    const int sr  = tid >> 4;        // A-stage row 0..15
    const int sc4 = (tid & 15) * 4;  // A-stage col (float4), 0..60
    const int ra  = min(r0 + sr, M - 1);
    const int k0  = sk * KS;

    for (int kc = k0; kc < k0 + KS; kc += 64) {
        // A tile 16x64
        *(float4*)&As[sr * 64 + sc4] = *(const float4*)(A + (size_t)ra * K + kc + sc4);
        // W tile 64x128 (coalesced float4)
#pragma unroll
        for (int l = 0; l < 8; l++) {
            int idx = tid + l * 256;       // float4 index 0..2047
            int wr  = idx >> 5;            // 0..63
            int wc  = (idx & 31) * 4;
            *(float4*)&Ws[wr * 128 + wc] =
                *(const float4*)(W + (size_t)(kc + wr) * 128 + wc);
        }
        __syncthreads();
        for (int k = 0; k < 64; k += 4) {
            float w0 = Ws[(k + 0) * 128 + col];
            float w1 = Ws[(k + 1) * 128 + col];
            float w2 = Ws[(k + 2) * 128 + col];
            float w3 = Ws[(k + 3) * 128 + col];
#pragma unroll
            for (int r = 0; r < 8; r++) {
                float4 av = *(const float4*)&As[(rh * 8 + r) * 64 + k];
                acc[r] = fmaf(av.x, w0, acc[r]);
                acc[r] = fmaf(av.y, w1, acc[r]);
                acc[r] = fmaf(av.z, w2, acc[r]);
                acc[r] = fmaf(av.w, w3, acc[r]);
            }
        }
        __syncthreads();
    }
#pragma unroll
    for (int r = 0; r < 8; r++) {
        int row = r0 + rh * 8 + r;
        if (row < M) Cp[((size_t)sk * M + row) * 128 + col] = acc[r];
    }
}

// Layer-2: stage A = relu(sum_sk Cp + b1), W2 staged in LDS (two 64-row panels),
// write xFd = relu(A @ W2 + b2). 8 rows/block.
__global__ __launch_bounds__(256) void k_mlp2(const float* __restrict__ Cp,
                                              const float* __restrict__ b1v,
                                              const float* __restrict__ W,
                                              const float* __restrict__ b2v,
                                              float* __restrict__ Cout, int M, int SK) {
    __shared__ float As[8 * 128];
    __shared__ float Ws[64 * 128];
    const int tid = threadIdx.x;
    const int r0  = blockIdx.x * 8;
    const int col = tid & 127;
    const int rh  = tid >> 7;

    const int sr  = tid >> 5;
    const int sc4 = (tid & 31) * 4;
    const int ra  = min(r0 + sr, M - 1);
    // reduce partials + bias + relu during staging
    float4 s = {0.f, 0.f, 0.f, 0.f};
    for (int sk = 0; sk < SK; sk++) {
        float4 v = *(const float4*)(Cp + ((size_t)sk * M + ra) * 128 + sc4);
        s.x += v.x; s.y += v.y; s.z += v.z; s.w += v.w;
    }
    float4 bb = *(const float4*)(b1v + sc4);
    s.x = fmaxf(s.x + bb.x, 0.f);
    s.y = fmaxf(s.y + bb.y, 0.f);
    s.z = fmaxf(s.z + bb.z, 0.f);
    s.w = fmaxf(s.w + bb.w, 0.f);
    *(float4*)&As[sr * 128 + sc4] = s;

    float acc[4] = {};
    for (int kc = 0; kc < 128; kc += 64) {
#pragma unroll
        for (int l = 0; l < 8; l++) {
            int idx = tid + l * 256;
            int wr  = idx >> 5;
            int wc  = (idx & 31) * 4;
            *(float4*)&Ws[wr * 128 + wc] =
                *(const float4*)(W + (size_t)(kc + wr) * 128 + wc);
        }
        __syncthreads();
        for (int k = 0; k < 64; k += 4) {
            float w0 = Ws[(k + 0) * 128 + col];
            float w1 = Ws[(k + 1) * 128 + col];
            float w2 = Ws[(k + 2) * 128 + col];
            float w3 = Ws[(k + 3) * 128 + col];
#pragma unroll
            for (int r = 0; r < 4; r++) {
                float4 av = *(const float4*)&As[(rh * 4 + r) * 128 + kc + k];
                acc[r] = fmaf(av.x, w0, acc[r]);
                acc[r] = fmaf(av.y, w1, acc[r]);
                acc[r] = fmaf(av.z, w2, acc[r]);
                acc[r] = fmaf(av.w, w3, acc[r]);
            }
        }
        __syncthreads();
    }
    float b2 = b2v[col];
#pragma unroll
    for (int r = 0; r < 4; r++) {
        int row = r0 + rh * 4 + r;
        if (row < M) Cout[(size_t)row * 128 + col] = fmaxf(acc[r] + b2, 0.f);
    }
}

// Edge bucketing pass A: deg[dst]++ for edges with dst < nD.
__global__ __launch_bounds__(256) void k_deg(const int* __restrict__ ei,
                                             int* __restrict__ deg, int E, int nD) {
    int e = blockIdx.x * 256 + threadIdx.x;
    if (e >= E) return;
    int dst = ei[E + e];
    if (dst < nD) atomicAdd(deg + dst, 1);
}

// Generic pass B: single-block Hillis-Steele scan -> exclusive offsets + cursor.
__global__ __launch_bounds__(1024) void k_scan(const int* __restrict__ deg,
                                               int* __restrict__ off,
                                               int* __restrict__ cursor, int nD) {
    __shared__ int s[1024];
    int t = threadIdx.x;
    int v = (t < nD) ? deg[t] : 0;
    s[t] = v;
    __syncthreads();
    for (int o = 1; o < 1024; o <<= 1) {
        int add = (t >= o) ? s[t - o] : 0;
        __syncthreads();
        s[t] += add;
        __syncthreads();
    }
    int excl = s[t] - v;
    if (t < nD) {
        off[t]    = excl;
        cursor[t] = excl;
    }
    if (t == nD - 1) off[nD] = s[t];
}

// Edge pass C: scatter src indices of surviving edges into per-dst buckets.
__global__ __launch_bounds__(256) void k_fill(const int* __restrict__ ei,
                                              int* __restrict__ cursor,
                                              int* __restrict__ srcIdx, int E, int nD) {
    int e = blockIdx.x * 256 + threadIdx.x;
    if (e >= E) return;
    int dst = ei[E + e];
    if (dst >= nD) return;
    int pos = atomicAdd(cursor + dst, 1);
    srcIdx[pos] = ei[e];
}

// Edge pass D: one block per dst drug; src rows gathered from xFd or pE.
__global__ __launch_bounds__(128) void k_agg(const int* __restrict__ off,
                                             const int* __restrict__ srcIdx,
                                             const float* __restrict__ xFd,
                                             const float* __restrict__ pE,
                                             float* __restrict__ agg,
                                             float* __restrict__ cnt, int nD) {
    int d = blockIdx.x;
    int c = threadIdx.x;
    int s0 = off[d], s1 = off[d + 1];
    float acc = 0.f;
    for (int j = s0; j < s1; j++) {
        int src = srcIdx[j];
        const float* base = (src < nD) ? (xFd + (size_t)src * 128)
                                       : (pE + (size_t)(src - nD) * 128);
        acc += base[c];
    }
    agg[(size_t)d * 128 + c] = acc;
    if (c == 0) cnt[d] = (float)(s1 - s0);
}

// tpl bucketing pass A: deg2[a]++ (all a < nD by construction).
__global__ __launch_bounds__(256) void k_deg2(const int* __restrict__ tpl,
                                              int* __restrict__ deg2, int T) {
    int t = blockIdx.x * 256 + threadIdx.x;
    if (t >= T) return;
    atomicAdd(deg2 + tpl[2 * t], 1);
}

// tpl pass C: scatter packed (t, b) pairs into per-a buckets.
__global__ __launch_bounds__(256) void k_fill2(const int* __restrict__ tpl,
                                               int* __restrict__ cursor2,
                                               int2* __restrict__ pairs, int T) {
    int t = blockIdx.x * 256 + threadIdx.x;
    if (t >= T) return;
    int a = tpl[2 * t];
    int b = tpl[2 * t + 1];
    int pos = atomicAdd(cursor2 + a, 1);
    pairs[pos] = make_int2(t, b);
}

// fX = relu((agg/max(cnt,1)) @ Wl + bl + xFd @ Wr). Wl/Wr staged in LDS as
// 32-row panels (4 phases). 8 rows/block.
__global__ __launch_bounds__(256) void k_sage(const float* __restrict__ agg,
                                              const float* __restrict__ cnt,
                                              const float* __restrict__ xFd,
                                              const float* __restrict__ Wl,
                                              const float* __restrict__ bl,
                                              const float* __restrict__ Wr,
                                              float* __restrict__ fX, int M) {
    __shared__ float ms[8 * 128];
    __shared__ float xs[8 * 128];
    __shared__ float Wls[32 * 128];
    __shared__ float Wrs[32 * 128];
    const int tid = threadIdx.x;
    const int r0  = blockIdx.x * 8;
    const int col = tid & 127;
    const int rh  = tid >> 7;

    const int sr  = tid >> 5;
    const int sc4 = (tid & 31) * 4;
    const int ra  = min(r0 + sr, M - 1);
    float inv = 1.0f / fmaxf(cnt[ra], 1.0f);
    float4 av = *(const float4*)(agg + (size_t)ra * 128 + sc4);
    av.x *= inv; av.y *= inv; av.z *= inv; av.w *= inv;
    *(float4*)&ms[sr * 128 + sc4] = av;
    *(float4*)&xs[sr * 128 + sc4] = *(const float4*)(xFd + (size_t)ra * 128 + sc4);

    float acc[4] = {};
    for (int kc = 0; kc < 128; kc += 32) {
#pragma unroll
        for (int l = 0; l < 4; l++) {
            int idx = tid + l * 256;  // float4 index 0..1023
            int wr  = idx >> 5;       // 0..31
            int wc  = (idx & 31) * 4;
            *(float4*)&Wls[wr * 128 + wc] =
                *(const float4*)(Wl + (size_t)(kc + wr) * 128 + wc);
            *(float4*)&Wrs[wr * 128 + wc] =
                *(const float4*)(Wr + (size_t)(kc + wr) * 128 + wc);
        }
        __syncthreads();
        for (int u = 0; u < 32; u++) {
            float wl = Wls[u * 128 + col];
            float wr = Wrs[u * 128 + col];
#pragma unroll
            for (int r = 0; r < 4; r++) {
                acc[r] = fmaf(ms[(rh * 4 + r) * 128 + kc + u], wl, acc[r]);
                acc[r] = fmaf(xs[(rh * 4 + r) * 128 + kc + u], wr, acc[r]);
            }
        }
        __syncthreads();
    }
    float bb = bl[col];
#pragma unroll
    for (int r = 0; r < 4; r++) {
        int row = r0 + rh * 4 + r;
        if (row < M) fX[(size_t)row * 128 + col] = fmaxf(acc[r] + bb, 0.f);
    }
}

// Gather outW2[:, sampleSes] into padded (128 x 512) + outB2[sampleSes] into 512.
__global__ __launch_bounds__(256) void k_w2g(const float* __restrict__ oW2,
                                             const float* __restrict__ oB2,
                                             const int* __restrict__ sSes,
                                             float* __restrict__ W2p,
                                             float* __restrict__ B2p, int nSe, int S) {
    int t = blockIdx.x * 256 + threadIdx.x;
    if (t < 128 * 512) {
        int k = t >> 9, j = t & 511;
        W2p[t] = (j < S) ? oW2[(size_t)k * nSe + sSes[j]] : 0.f;
    } else {
        int j = t - 128 * 512;
        if (j < 512) B2p[j] = (j < S) ? oB2[sSes[j]] : 0.f;
    }
}

// Generic small GEMM (used for M2 = outW1 @ W2p): C(M x 512) = A(M x 128) @ B.
__global__ __launch_bounds__(256) void k_g16(const float* __restrict__ A,
                                             const float* __restrict__ B,
                                             float* __restrict__ C, int M,
                                             int ldb, int ldc) {
    __shared__ float As[16 * 128];
    const int tid = threadIdx.x;
    const int r0  = blockIdx.x * 16;
    const int cb  = blockIdx.y;
    const int c4  = (tid & 31) * 4;
    const int rg  = tid >> 5;

#pragma unroll
    for (int l = 0; l < 2; l++) {
        int idx = tid + l * 256;
        int row = idx >> 5, cc = (idx & 31) * 4;
        int ra  = min(r0 + row, M - 1);
        *(float4*)&As[row * 128 + cc] = *(const float4*)(A + (size_t)ra * 128 + cc);
    }
    __syncthreads();

    const float* Bp = B + cb * 128 + c4;
    float acc[2][4] = {};
    for (int k = 0; k < 128; k += 4) {
        float4 a0 = *(const float4*)&As[(rg * 2 + 0) * 128 + k];
        float4 a1 = *(const float4*)&As[(rg * 2 + 1) * 128 + k];
        const float* pa0 = &a0.x;
        const float* pa1 = &a1.x;
#pragma unroll
        for (int u = 0; u < 4; u++) {
            float4 wv = *(const float4*)(Bp + (size_t)(k + u) * ldb);
            float v0 = pa0[u], v1 = pa1[u];
            acc[0][0] = fmaf(v0, wv.x, acc[0][0]);
            acc[0][1] = fmaf(v0, wv.y, acc[0][1]);
            acc[0][2] = fmaf(v0, wv.z, acc[0][2]);
            acc[0][3] = fmaf(v0, wv.w, acc[0][3]);
            acc[1][0] = fmaf(v1, wv.x, acc[1][0]);
            acc[1][1] = fmaf(v1, wv.y, acc[1][1]);
            acc[1][2] = fmaf(v1, wv.z, acc[1][2]);
            acc[1][3] = fmaf(v1, wv.w, acc[1][3]);
        }
    }
#pragma unroll
    for (int r = 0; r < 2; r++) {
        int row = r0 + rg * 2 + r;
        if (row < M) {
            float4 o = {acc[r][0], acc[r][1], acc[r][2], acc[r][3]};
            *(float4*)(C + (size_t)row * ldc + cb * 128 + c4) = o;
        }
    }
}

// Cvec[j] = sum_k oB1[k] * W2p[k][j] + B2p[j], j in [0,512)
__global__ __launch_bounds__(256) void k_cvec(const float* __restrict__ oB1,
                                              const float* __restrict__ W2p,
                                              const float* __restrict__ B2p,
                                              float* __restrict__ Cvec) {
    int j = blockIdx.x * 256 + threadIdx.x;
    if (j >= 512) return;
    float s = B2p[j];
    for (int k = 0; k < 128; k++) s = fmaf(oB1[k], W2p[k * 512 + j], s);
    Cvec[j] = s;
}

// PPc = fX @ M2_hi + Cvec, QQc = fX @ M2_lo — compact (nD x 512) each so the
// k_final2 QQ gather footprint is a dense 2 MB (per-XCD L2 resident).
// grid (ceil(M/16), 8): cb 0..3 -> PPc (+Cvec), cb 4..7 -> QQc. B in LDS.
__global__ __launch_bounds__(256) void k_pq(const float* __restrict__ A,
                                            const float* __restrict__ M2,
                                            const float* __restrict__ Cvec,
                                            float* __restrict__ PPc,
                                            float* __restrict__ QQc, int M) {
    __shared__ float As[16 * 128];
    __shared__ float Bs[64 * 128];
    const int tid = threadIdx.x;
    const int r0  = blockIdx.x * 16;
    const int cb  = blockIdx.y;  // 0..7
    const int c4  = (tid & 31) * 4;
    const int rg  = tid >> 5;

    const float* B = M2 + (size_t)(cb >> 2) * (128 * 512) + (cb & 3) * 128;

#pragma unroll
    for (int l = 0; l < 2; l++) {
        int idx = tid + l * 256;
        int row = idx >> 5, cc = (idx & 31) * 4;
        int ra  = min(r0 + row, M - 1);
        *(float4*)&As[row * 128 + cc] = *(const float4*)(A + (size_t)ra * 128 + cc);
    }

    float acc[2][4] = {};
    for (int kc = 0; kc < 128; kc += 64) {
#pragma unroll
        for (int l = 0; l < 8; l++) {
            int idx = tid + l * 256;  // float4 index 0..2047
            int wr  = idx >> 5;       // 0..63
            int wc  = (idx & 31) * 4;
            *(float4*)&Bs[wr * 128 + wc] =
                *(const float4*)(B + (size_t)(kc + wr) * 512 + wc);
        }
        __syncthreads();
        for (int k = 0; k < 64; k += 4) {
            float4 a0 = *(const float4*)&As[(rg * 2 + 0) * 128 + kc + k];
            float4 a1 = *(const float4*)&As[(rg * 2 + 1) * 128 + kc + k];
            const float* pa0 = &a0.x;
            const float* pa1 = &a1.x;
#pragma unroll
            for (int u = 0; u < 4; u++) {
                float4 wv = *(const float4*)&Bs[(k + u) * 128 + c4];
                float v0 = pa0[u], v1 = pa1[u];
                acc[0][0] = fmaf(v0, wv.x, acc[0][0]);
                acc[0][1] = fmaf(v0, wv.y, acc[0][1]);
                acc[0][2] = fmaf(v0, wv.z, acc[0][2]);
                acc[0][3] = fmaf(v0, wv.w, acc[0][3]);
                acc[1][0] = fmaf(v1, wv.x, acc[1][0]);
                acc[1][1] = fmaf(v1, wv.y, acc[1][1]);
                acc[1][2] = fmaf(v1, wv.z, acc[1][2]);
                acc[1][3] = fmaf(v1, wv.w, acc[1][3]);
            }
        }
        __syncthreads();
    }
    float4 cv = {0.f, 0.f, 0.f, 0.f};
    if (cb < 4) cv = *(const float4*)(Cvec + (cb & 3) * 128 + c4);
    float* dst = (cb < 4) ? PPc : QQc;
    int col = (cb & 3) * 128 + c4;
#pragma unroll
    for (int r = 0; r < 2; r++) {
        int row = r0 + rg * 2 + r;
        if (row < M) {
            float4 o = {acc[r][0] + cv.x, acc[r][1] + cv.y, acc[r][2] + cv.z,
                        acc[r][3] + cv.w};
            *(float4*)(dst + (size_t)row * 512 + col) = o;
        }
    }
}

// Bucketed final: block (d, yc) handles tpl pairs whose a == d.
// PP'[d] lives in registers (loaded once); QQ gathers hit the dense 2 MB QQc.
// 256 threads = 2 lane-halves, each walking an interleaved entry stream.
__global__ __launch_bounds__(256) void k_final2(const int* __restrict__ off2,
                                                const int2* __restrict__ pairs,
                                                const float* __restrict__ PPc,
                                                const float* __restrict__ QQc,
                                                float* __restrict__ out, int S) {
    const int d   = blockIdx.x;
    const int i   = threadIdx.x & 127;
    const int h   = threadIdx.x >> 7;
    const int sub = blockIdx.y * 2 + h;  // 0..7
    const int s0  = off2[d], s1 = off2[d + 1];
    if (i >= (S >> 2)) return;
    float4 p = ((const float4*)(PPc + (size_t)d * 512))[i];
    for (int j = s0 + sub; j < s1; j += 8) {
        int2 tb  = pairs[j];
        float4 q = ((const float4*)(QQc + (size_t)tb.y * 512))[i];
        float o0 = hshrink(p.x + q.x);
        float o1 = hshrink(p.y + q.y);
        float o2 = hshrink(p.z + q.z);
        float o3 = hshrink(p.w + q.w);
        float* po = out + (size_t)tb.x * S + i * 4;
        __builtin_nontemporal_store(o0, po + 0);
        __builtin_nontemporal_store(o1, po + 1);
        __builtin_nontemporal_store(o2, po + 2);
        __builtin_nontemporal_store(o3, po + 3);
    }
}

extern "C" void kernel_launch(void* const* d_in, const int* in_sizes, int n_in,
                              void* d_out, int out_size, void* d_ws, size_t ws_size,
                              hipStream_t stream) {
    const float* dF   = (const float*)d_in[0];
    const int*   ei   = (const int*)d_in[1];
    const int*   tpl  = (const int*)d_in[2];
    const int*   sSes = (const int*)d_in[3];
    const float* W1   = (const float*)d_in[4];
    const float* b1   = (const float*)d_in[5];
    const float* W2   = (const float*)d_in[6];
    const float* b2   = (const float*)d_in[7];
    const float* pE   = (const float*)d_in[8];
    const float* sWl  = (const float*)d_in[9];
    const float* sBl  = (const float*)d_in[10];
    const float* sWr  = (const float*)d_in[11];
    const float* oW1  = (const float*)d_in[12];
    const float* oB1  = (const float*)d_in[13];
    const float* oW2  = (const float*)d_in[14];
    const float* oB2  = (const float*)d_in[15];

    const int D    = 128;
    const int F    = in_sizes[4] / D;   // 2048
    const int nD   = in_sizes[0] / F;   // 1000
    const int E    = in_sizes[1] / 2;   // 640000
    const int T    = in_sizes[2] / 2;   // 150000
    const int S    = in_sizes[3];       // 500
    const int nSe  = in_sizes[15];      // 964
    const int SK   = 4;                 // split-K for layer-1 MLP

    float* ws   = (float*)d_ws;
    float* xFd  = ws;                                // nD*128  (drug embeddings)
    float* h1p  = xFd + (size_t)nD * D;              // SK*nD*128 (layer-1 partials)
    float* agg  = h1p + (size_t)SK * nD * D;         // nD*128
    float* cnt  = agg + (size_t)nD * D;              // nD (padded to 1024)
    float* fX   = cnt + 1024;                        // nD*128
    float* W2p  = fX + (size_t)nD * D;               // 128*512
    float* B2p  = W2p + 128 * 512;                   // 512
    float* M2   = B2p + 512;                         // 256*512
    float* Cvec = M2 + 256 * 512;                    // 512
    float* PPc  = Cvec + 512;                        // nD*512 (2 MB)
    float* QQc  = PPc + (size_t)nD * 512;            // nD*512 (2 MB)
    int2* pairs = (int2*)(QQc + (size_t)nD * 512);   // T pairs (8B-aligned)
    int* deg    = (int*)(pairs + T);                 // 1024
    int* deg2   = deg + 1024;                        // 1024 (contiguous w/ deg)
    int* off    = deg2 + 1024;                       // 1025
    int* cursor = off + 1025;                        // 1024
    int* off2   = cursor + 1024;                     // 1025
    int* cursor2= off2 + 1025;                       // 1024
    int* srcIdx = cursor2 + 1024;                    // <= E

    // layer-1 split-K partials; layer-2 fuses the reduction + bias + relu
    {
        dim3 g((nD + 15) / 16, SK);
        k_mlp1<<<g, 256, 0, stream>>>(dF, W1, h1p, nD, F, F / SK);
    }
    k_mlp2<<<(nD + 7) / 8, 256, 0, stream>>>(h1p, b1, W2, b2, xFd, nD, SK);
    // zero both degree arrays in one memset (adjacent)
    hipMemsetAsync(deg, 0, 2048 * sizeof(int), stream);
    // edge bucketing + aggregation
    k_deg<<<(E + 255) / 256, 256, 0, stream>>>(ei, deg, E, nD);
    k_scan<<<1, 1024, 0, stream>>>(deg, off, cursor, nD);
    k_fill<<<(E + 255) / 256, 256, 0, stream>>>(ei, cursor, srcIdx, E, nD);
    k_agg<<<nD, 128, 0, stream>>>(off, srcIdx, xFd, pE, agg, cnt, nD);
    // tpl bucketing by drug a (for the bucketed final)
    k_deg2<<<(T + 255) / 256, 256, 0, stream>>>(tpl, deg2, T);
    k_scan<<<1, 1024, 0, stream>>>(deg2, off2, cursor2, nD);
    k_fill2<<<(T + 255) / 256, 256, 0, stream>>>(tpl, cursor2, pairs, T);
    // SAGE rows 0..nD-1 -> fX
    k_sage<<<(nD + 7) / 8, 256, 0, stream>>>(agg, cnt, xFd, sWl, sBl, sWr, fX, nD);
    // gather sampled outW2 columns (padded to 512)
    k_w2g<<<(128 * 512 + 512 + 255) / 256, 256, 0, stream>>>(oW2, oB2, sSes, W2p, B2p,
                                                             nSe, S);
    // M2 = outW1 (256x128) @ W2p (128x512)
    {
        dim3 g((256 + 15) / 16, 4);
        k_g16<<<g, 256, 0, stream>>>(oW1, W2p, M2, 256, 512, 512);
    }
    // Cvec = oB1 @ W2p + B2p
    k_cvec<<<2, 256, 0, stream>>>(oB1, W2p, B2p, Cvec);
    // PPc (fX@M2_hi + Cvec) and QQc (fX@M2_lo), compact layouts
    {
        dim3 g((nD + 15) / 16, 8);
        k_pq<<<g, 256, 0, stream>>>(fX, M2, Cvec, PPc, QQc, nD);
    }
    // bucketed final streaming epilogue
    {
        dim3 g(nD, 4);
        k_final2<<<g, 256, 0, stream>>>(off2, pairs, PPc, QQc, (float*)d_out, S);
    }
}

// Round 4
// 461.457 us; speedup vs baseline: 1.2404x; 1.2404x over previous
//
#include <hip/hip_runtime.h>
#include <cstddef>

// ---------------------------------------------------------------------------
// Decagon pipeline, fp32, algebraically collapsed output layers.
// Key identity: hardshrink(v, 1e-6) == v to within 1e-6, so
//   out2[t] = hshrink( xd[t] @ oW1 @ W2s + oB1 @ W2s + oB2s )
//           = hshrink( PP'[a] + QQ[b] ),  PP' = fX@M2_hi + Cvec folded in.
//
// R1: bucketed edge aggregation replacing 3.9M float atomicAdds. 765 -> 567.
// R2: split-K + LDS-staged W for latency-bound MLP; pq merged. 567 -> 509.
// R3: FAILED (+63): bucketing k_final by drug a fixed the gather but broke
//     write streaming (random-t 2KB rows across 300 MB). Reverted.
// R4: launch-count attack: fold cvec into g16 (row 257 of M2); fuse agg+sage
//     (mean row in LDS -> immediate SAGE matmul, no agg roundtrip);
//     horizontal-fuse {mlp1,deg,w2g}, {mlp2,scan}, {fill,g16}.
//     13 graph nodes -> 7.
// ---------------------------------------------------------------------------

__device__ __forceinline__ float hshrink(float v) {
    return (fabsf(v) > 1e-6f) ? v : 0.0f;
}

// ===========================================================================
// K1: fused {mlp1 partials | edge degree count | outW2 column gather}
//   mlp1: Cp[sk][row][col] = A[row, sk*KS:(sk+1)*KS] @ W-chunk (LDS-staged)
//   deg:  deg[dst]++ for edges with dst < nD
//   w2g:  W2p (128x512 padded) = oW2[:, sSes], B2p = oB2[sSes]
// ===========================================================================
__global__ __launch_bounds__(256) void k_fused1(
    const float* __restrict__ A, const float* __restrict__ W,
    float* __restrict__ Cp, int M, int K, int KS, int gx,
    const int* __restrict__ ei, int* __restrict__ deg, int E, int nD,
    const float* __restrict__ oW2, const float* __restrict__ oB2,
    const int* __restrict__ sSes, float* __restrict__ W2p,
    float* __restrict__ B2p, int nSe, int S,
    int nbMlp, int nbDeg) {
    __shared__ float sh[16 * 64 + 64 * 128];  // As | Ws (36 KB)
    const int b   = blockIdx.x;
    const int tid = threadIdx.x;

    if (b < nbMlp) {
        // ---- mlp1 branch ----
        float* As = sh;
        float* Ws = sh + 16 * 64;
        const int bx  = b % gx;
        const int sk  = b / gx;
        const int r0  = bx * 16;
        const int col = tid & 127;
        const int rh  = tid >> 7;  // 0/1 -> rows rh*8 .. rh*8+7
        float acc[8] = {};

        const int sr  = tid >> 4;        // A-stage row 0..15
        const int sc4 = (tid & 15) * 4;  // A-stage col (float4)
        const int ra  = min(r0 + sr, M - 1);
        const int k0  = sk * KS;

        for (int kc = k0; kc < k0 + KS; kc += 64) {
            *(float4*)&As[sr * 64 + sc4] =
                *(const float4*)(A + (size_t)ra * K + kc + sc4);
#pragma unroll
            for (int l = 0; l < 8; l++) {
                int idx = tid + l * 256;
                int wr  = idx >> 5;
                int wc  = (idx & 31) * 4;
                *(float4*)&Ws[wr * 128 + wc] =
                    *(const float4*)(W + (size_t)(kc + wr) * 128 + wc);
            }
            __syncthreads();
            for (int k = 0; k < 64; k += 4) {
                float w0 = Ws[(k + 0) * 128 + col];
                float w1 = Ws[(k + 1) * 128 + col];
                float w2 = Ws[(k + 2) * 128 + col];
                float w3 = Ws[(k + 3) * 128 + col];
#pragma unroll
                for (int r = 0; r < 8; r++) {
                    float4 av = *(const float4*)&As[(rh * 8 + r) * 64 + k];
                    acc[r] = fmaf(av.x, w0, acc[r]);
                    acc[r] = fmaf(av.y, w1, acc[r]);
                    acc[r] = fmaf(av.z, w2, acc[r]);
                    acc[r] = fmaf(av.w, w3, acc[r]);
                }
            }
            __syncthreads();
        }
#pragma unroll
        for (int r = 0; r < 8; r++) {
            int row = r0 + rh * 8 + r;
            if (row < M) Cp[((size_t)sk * M + row) * 128 + col] = acc[r];
        }
    } else if (b < nbMlp + nbDeg) {
        // ---- edge degree branch ----
        int e = (b - nbMlp) * 256 + tid;
        if (e < E) {
            int dst = ei[E + e];
            if (dst < nD) atomicAdd(deg + dst, 1);
        }
    } else {
        // ---- w2g branch ----
        int t = (b - nbMlp - nbDeg) * 256 + tid;
        if (t < 128 * 512) {
            int k = t >> 9, j = t & 511;
            W2p[t] = (j < S) ? oW2[(size_t)k * nSe + sSes[j]] : 0.f;
        } else if (t < 128 * 512 + 512) {
            int j = t - 128 * 512;
            B2p[j] = (j < S) ? oB2[sSes[j]] : 0.f;
        }
    }
}

// ===========================================================================
// K2: fused {mlp2 | scan}
//   mlp2: stage A = relu(sum_sk Cp + b1), xFd = relu(A @ W2 + b2)
//   scan: 256-thread exclusive scan of deg[0..1024) -> off, cursor
// ===========================================================================
__global__ __launch_bounds__(256) void k_fused2(
    const float* __restrict__ Cp, const float* __restrict__ b1v,
    const float* __restrict__ W, const float* __restrict__ b2v,
    float* __restrict__ Cout, int M, int SK,
    const int* __restrict__ deg, int* __restrict__ off,
    int* __restrict__ cursor, int nbMlp2) {
    __shared__ float sh[8 * 128 + 64 * 128];  // As | Ws (36 KB)
    const int b   = blockIdx.x;
    const int tid = threadIdx.x;

    if (b < nbMlp2) {
        // ---- mlp2 branch ----
        float* As = sh;
        float* Ws = sh + 8 * 128;
        const int r0  = b * 8;
        const int col = tid & 127;
        const int rh  = tid >> 7;

        const int sr  = tid >> 5;
        const int sc4 = (tid & 31) * 4;
        const int ra  = min(r0 + sr, M - 1);
        float4 s = {0.f, 0.f, 0.f, 0.f};
        for (int sk = 0; sk < SK; sk++) {
            float4 v = *(const float4*)(Cp + ((size_t)sk * M + ra) * 128 + sc4);
            s.x += v.x; s.y += v.y; s.z += v.z; s.w += v.w;
        }
        float4 bb = *(const float4*)(b1v + sc4);
        s.x = fmaxf(s.x + bb.x, 0.f);
        s.y = fmaxf(s.y + bb.y, 0.f);
        s.z = fmaxf(s.z + bb.z, 0.f);
        s.w = fmaxf(s.w + bb.w, 0.f);
        *(float4*)&As[sr * 128 + sc4] = s;

        float acc[4] = {};
        for (int kc = 0; kc < 128; kc += 64) {
#pragma unroll
            for (int l = 0; l < 8; l++) {
                int idx = tid + l * 256;
                int wr  = idx >> 5;
                int wc  = (idx & 31) * 4;
                *(float4*)&Ws[wr * 128 + wc] =
                    *(const float4*)(W + (size_t)(kc + wr) * 128 + wc);
            }
            __syncthreads();
            for (int k = 0; k < 64; k += 4) {
                float w0 = Ws[(k + 0) * 128 + col];
                float w1 = Ws[(k + 1) * 128 + col];
                float w2 = Ws[(k + 2) * 128 + col];
                float w3 = Ws[(k + 3) * 128 + col];
#pragma unroll
                for (int r = 0; r < 4; r++) {
                    float4 av = *(const float4*)&As[(rh * 4 + r) * 128 + kc + k];
                    acc[r] = fmaf(av.x, w0, acc[r]);
                    acc[r] = fmaf(av.y, w1, acc[r]);
                    acc[r] = fmaf(av.z, w2, acc[r]);
                    acc[r] = fmaf(av.w, w3, acc[r]);
                }
            }
            __syncthreads();
        }
        float b2 = b2v[col];
#pragma unroll
        for (int r = 0; r < 4; r++) {
            int row = r0 + rh * 4 + r;
            if (row < M) Cout[(size_t)row * 128 + col] = fmaxf(acc[r] + b2, 0.f);
        }
    } else {
        // ---- scan branch: 256 threads x 4 elements over deg[0..1024) ----
        int* s = (int*)sh;
        int4 v = ((const int4*)deg)[tid];
        int loc = v.x + v.y + v.z + v.w;
        s[tid] = loc;
        __syncthreads();
        for (int o = 1; o < 256; o <<= 1) {
            int add = (tid >= o) ? s[tid - o] : 0;
            __syncthreads();
            s[tid] += add;
            __syncthreads();
        }
        int run = s[tid] - loc;  // exclusive prefix of this thread's 4-group
        int i0  = tid * 4;
        off[i0 + 0] = run; cursor[i0 + 0] = run; run += v.x;
        off[i0 + 1] = run; cursor[i0 + 1] = run; run += v.y;
        off[i0 + 2] = run; cursor[i0 + 2] = run; run += v.z;
        off[i0 + 3] = run; cursor[i0 + 3] = run; run += v.w;
        if (tid == 255) off[1024] = run;
    }
}

// ===========================================================================
// K3: fused {fill | g16b}
//   fill: scatter src indices of surviving edges into per-dst buckets
//   g16b: M2(257x512) = [oW1; oB1] (257x128) @ W2p (128x512)
// ===========================================================================
__global__ __launch_bounds__(256) void k_fused3(
    const int* __restrict__ ei, int* __restrict__ cursor,
    int* __restrict__ srcIdx, int E, int nD,
    const float* __restrict__ oW1, const float* __restrict__ oB1,
    const float* __restrict__ W2p, float* __restrict__ M2, int nbFill) {
    __shared__ float As[16 * 128];
    const int b   = blockIdx.x;
    const int tid = threadIdx.x;

    if (b < nbFill) {
        // ---- fill branch ----
        int e = b * 256 + tid;
        if (e < E) {
            int dst = ei[E + e];
            if (dst < nD) {
                int pos = atomicAdd(cursor + dst, 1);
                srcIdx[pos] = ei[e];
            }
        }
    } else {
        // ---- g16b branch: 17 x-blocks x 4 col-blocks, M = 257 ----
        const int gb = b - nbFill;
        const int bx = gb % 17;
        const int cb = gb / 17;
        const int r0 = bx * 16;
        const int c4 = (tid & 31) * 4;
        const int rg = tid >> 5;

#pragma unroll
        for (int l = 0; l < 2; l++) {
            int idx = tid + l * 256;
            int row = idx >> 5, cc = (idx & 31) * 4;
            int ra  = min(r0 + row, 256);
            const float* ap = (ra < 256) ? (oW1 + (size_t)ra * 128) : oB1;
            *(float4*)&As[row * 128 + cc] = *(const float4*)(ap + cc);
        }
        __syncthreads();

        const float* Bp = W2p + cb * 128 + c4;
        float acc[2][4] = {};
        for (int k = 0; k < 128; k += 4) {
            float4 a0 = *(const float4*)&As[(rg * 2 + 0) * 128 + k];
            float4 a1 = *(const float4*)&As[(rg * 2 + 1) * 128 + k];
            const float* pa0 = &a0.x;
            const float* pa1 = &a1.x;
#pragma unroll
            for (int u = 0; u < 4; u++) {
                float4 wv = *(const float4*)(Bp + (size_t)(k + u) * 512);
                float v0 = pa0[u], v1 = pa1[u];
                acc[0][0] = fmaf(v0, wv.x, acc[0][0]);
                acc[0][1] = fmaf(v0, wv.y, acc[0][1]);
                acc[0][2] = fmaf(v0, wv.z, acc[0][2]);
                acc[0][3] = fmaf(v0, wv.w, acc[0][3]);
                acc[1][0] = fmaf(v1, wv.x, acc[1][0]);
                acc[1][1] = fmaf(v1, wv.y, acc[1][1]);
                acc[1][2] = fmaf(v1, wv.z, acc[1][2]);
                acc[1][3] = fmaf(v1, wv.w, acc[1][3]);
            }
        }
#pragma unroll
        for (int r = 0; r < 2; r++) {
            int row = r0 + rg * 2 + r;
            if (row < 257) {
                float4 o = {acc[r][0], acc[r][1], acc[r][2], acc[r][3]};
                *(float4*)(M2 + (size_t)row * 512 + cb * 128 + c4) = o;
            }
        }
    }
}

// ===========================================================================
// K4: fused agg + sage. One block per drug d (128 threads, one per col):
//   mean[c] = (sum over bucket of xF[src][c]) / max(deg,1)   (LDS)
//   fX[d][c] = relu(sum_k mean[k]*Wl[k][c] + xFd[d][k]*Wr[k][c] + bl[c])
// ===========================================================================
__global__ __launch_bounds__(128) void k_aggsage(
    const int* __restrict__ off, const int* __restrict__ srcIdx,
    const float* __restrict__ xFd, const float* __restrict__ pE,
    const float* __restrict__ Wl, const float* __restrict__ bl,
    const float* __restrict__ Wr, float* __restrict__ fX, int nD) {
    __shared__ float ms[128];
    __shared__ float xs[128];
    const int d = blockIdx.x;
    const int c = threadIdx.x;
    const int s0 = off[d], s1 = off[d + 1];

    float acc = 0.f;
    int j = s0;
    for (; j + 4 <= s1; j += 4) {
        int i0 = srcIdx[j + 0];
        int i1 = srcIdx[j + 1];
        int i2 = srcIdx[j + 2];
        int i3 = srcIdx[j + 3];
        const float* p0 = (i0 < nD) ? (xFd + (size_t)i0 * 128) : (pE + (size_t)(i0 - nD) * 128);
        const float* p1 = (i1 < nD) ? (xFd + (size_t)i1 * 128) : (pE + (size_t)(i1 - nD) * 128);
        const float* p2 = (i2 < nD) ? (xFd + (size_t)i2 * 128) : (pE + (size_t)(i2 - nD) * 128);
        const float* p3 = (i3 < nD) ? (xFd + (size_t)i3 * 128) : (pE + (size_t)(i3 - nD) * 128);
        acc += p0[c]; acc += p1[c]; acc += p2[c]; acc += p3[c];
    }
    for (; j < s1; j++) {
        int src = srcIdx[j];
        const float* p = (src < nD) ? (xFd + (size_t)src * 128)
                                    : (pE + (size_t)(src - nD) * 128);
        acc += p[c];
    }
    float inv = 1.0f / fmaxf((float)(s1 - s0), 1.0f);
    ms[c] = acc * inv;
    xs[c] = xFd[(size_t)d * 128 + c];
    __syncthreads();

    float a1 = 0.f, a2 = 0.f;
#pragma unroll 4
    for (int k = 0; k < 128; k++) {
        a1 = fmaf(ms[k], Wl[(size_t)k * 128 + c], a1);
        a2 = fmaf(xs[k], Wr[(size_t)k * 128 + c], a2);
    }
    fX[(size_t)d * 128 + c] = fmaxf(a1 + a2 + bl[c], 0.f);
}

// ===========================================================================
// K5: PPc = fX @ M2[0:128] + (M2[256] + B2p),  QQc = fX @ M2[128:256]
//   grid (ceil(M/16), 8): cb 0..3 -> PPc (+cvec), cb 4..7 -> QQc. B in LDS.
// ===========================================================================
__global__ __launch_bounds__(256) void k_pq(const float* __restrict__ A,
                                            const float* __restrict__ M2,
                                            const float* __restrict__ B2p,
                                            float* __restrict__ PPc,
                                            float* __restrict__ QQc, int M) {
    __shared__ float As[16 * 128];
    __shared__ float Bs[64 * 128];
    const int tid = threadIdx.x;
    const int r0  = blockIdx.x * 16;
    const int cb  = blockIdx.y;  // 0..7
    const int c4  = (tid & 31) * 4;
    const int rg  = tid >> 5;

    const float* B = M2 + (size_t)(cb >> 2) * (128 * 512) + (cb & 3) * 128;

#pragma unroll
    for (int l = 0; l < 2; l++) {
        int idx = tid + l * 256;
        int row = idx >> 5, cc = (idx & 31) * 4;
        int ra  = min(r0 + row, M - 1);
        *(float4*)&As[row * 128 + cc] = *(const float4*)(A + (size_t)ra * 128 + cc);
    }

    float acc[2][4] = {};
    for (int kc = 0; kc < 128; kc += 64) {
#pragma unroll
        for (int l = 0; l < 8; l++) {
            int idx = tid + l * 256;
            int wr  = idx >> 5;
            int wc  = (idx & 31) * 4;
            *(float4*)&Bs[wr * 128 + wc] =
                *(const float4*)(B + (size_t)(kc + wr) * 512 + wc);
        }
        __syncthreads();
        for (int k = 0; k < 64; k += 4) {
            float4 a0 = *(const float4*)&As[(rg * 2 + 0) * 128 + kc + k];
            float4 a1 = *(const float4*)&As[(rg * 2 + 1) * 128 + kc + k];
            const float* pa0 = &a0.x;
            const float* pa1 = &a1.x;
#pragma unroll
            for (int u = 0; u < 4; u++) {
                float4 wv = *(const float4*)&Bs[(k + u) * 128 + c4];
                float v0 = pa0[u], v1 = pa1[u];
                acc[0][0] = fmaf(v0, wv.x, acc[0][0]);
                acc[0][1] = fmaf(v0, wv.y, acc[0][1]);
                acc[0][2] = fmaf(v0, wv.z, acc[0][2]);
                acc[0][3] = fmaf(v0, wv.w, acc[0][3]);
                acc[1][0] = fmaf(v1, wv.x, acc[1][0]);
                acc[1][1] = fmaf(v1, wv.y, acc[1][1]);
                acc[1][2] = fmaf(v1, wv.z, acc[1][2]);
                acc[1][3] = fmaf(v1, wv.w, acc[1][3]);
            }
        }
        __syncthreads();
    }
    // cvec (= M2 row 256 + B2p) folded into the PP half
    float4 cv = {0.f, 0.f, 0.f, 0.f};
    int colb = (cb & 3) * 128 + c4;
    if (cb < 4) {
        float4 m  = *(const float4*)(M2 + (size_t)256 * 512 + colb);
        float4 b2 = *(const float4*)(B2p + colb);
        cv.x = m.x + b2.x; cv.y = m.y + b2.y;
        cv.z = m.z + b2.z; cv.w = m.w + b2.w;
    }
    float* dst = (cb < 4) ? PPc : QQc;
#pragma unroll
    for (int r = 0; r < 2; r++) {
        int row = r0 + rg * 2 + r;
        if (row < M) {
            float4 o = {acc[r][0] + cv.x, acc[r][1] + cv.y, acc[r][2] + cv.z,
                        acc[r][3] + cv.w};
            *(float4*)(dst + (size_t)row * 512 + colb) = o;
        }
    }
}

// ===========================================================================
// K6: out[t] = hshrink(PPc[a] + QQc[b]). Sequential t -> streaming writes.
// ===========================================================================
__global__ __launch_bounds__(256) void k_final(const int2* __restrict__ tpl2,
                                               const float* __restrict__ PPc,
                                               const float* __restrict__ QQc,
                                               float* __restrict__ out, int T, int S) {
    int t = blockIdx.x * 2 + (threadIdx.x >> 7);
    int i = threadIdx.x & 127;
    if (t >= T || i >= (S >> 2)) return;
    int2 ab = tpl2[t];
    float4 p = ((const float4*)(PPc + (size_t)ab.x * 512))[i];
    float4 q = ((const float4*)(QQc + (size_t)ab.y * 512))[i];
    float o0 = hshrink(p.x + q.x);
    float o1 = hshrink(p.y + q.y);
    float o2 = hshrink(p.z + q.z);
    float o3 = hshrink(p.w + q.w);
    float* po = out + (size_t)t * S + i * 4;
    __builtin_nontemporal_store(o0, po + 0);
    __builtin_nontemporal_store(o1, po + 1);
    __builtin_nontemporal_store(o2, po + 2);
    __builtin_nontemporal_store(o3, po + 3);
}

extern "C" void kernel_launch(void* const* d_in, const int* in_sizes, int n_in,
                              void* d_out, int out_size, void* d_ws, size_t ws_size,
                              hipStream_t stream) {
    const float* dF   = (const float*)d_in[0];
    const int*   ei   = (const int*)d_in[1];
    const int*   tpl  = (const int*)d_in[2];
    const int*   sSes = (const int*)d_in[3];
    const float* W1   = (const float*)d_in[4];
    const float* b1   = (const float*)d_in[5];
    const float* W2   = (const float*)d_in[6];
    const float* b2   = (const float*)d_in[7];
    const float* pE   = (const float*)d_in[8];
    const float* sWl  = (const float*)d_in[9];
    const float* sBl  = (const float*)d_in[10];
    const float* sWr  = (const float*)d_in[11];
    const float* oW1  = (const float*)d_in[12];
    const float* oB1  = (const float*)d_in[13];
    const float* oW2  = (const float*)d_in[14];
    const float* oB2  = (const float*)d_in[15];

    const int D    = 128;
    const int F    = in_sizes[4] / D;   // 2048
    const int nD   = in_sizes[0] / F;   // 1000
    const int E    = in_sizes[1] / 2;   // 640000
    const int T    = in_sizes[2] / 2;   // 150000
    const int S    = in_sizes[3];       // 500
    const int nSe  = in_sizes[15];      // 964
    const int SK   = 4;                 // split-K for layer-1 MLP

    float* ws   = (float*)d_ws;
    float* xFd  = ws;                                // nD*128
    float* h1p  = xFd + (size_t)nD * D;              // SK*nD*128
    float* fX   = h1p + (size_t)SK * nD * D;         // nD*128
    float* W2p  = fX + (size_t)nD * D;               // 128*512
    float* B2p  = W2p + 128 * 512;                   // 512
    float* M2   = B2p + 512;                         // 257*512
    float* PPc  = M2 + 257 * 512;                    // nD*512 (2 MB)
    float* QQc  = PPc + (size_t)nD * 512;            // nD*512 (2 MB)
    int* deg    = (int*)(QQc + (size_t)nD * 512);    // 1024 (16B-aligned)
    int* off    = deg + 1024;                        // 1025
    int* cursor = off + 1025;                        // 1024
    int* srcIdx = cursor + 1024 + 3;                 // <= E (keep 16B align)

    const int gx     = (nD + 15) / 16;               // 63
    const int nbMlp  = gx * SK;                      // 252
    const int nbDeg  = (E + 255) / 256;              // 2500
    const int nbW2g  = (128 * 512 + 512 + 255) / 256;  // 258
    const int nbMlp2 = (nD + 7) / 8;                 // 125
    const int nbFill = (E + 255) / 256;              // 2500
    const int nbG16  = 17 * 4;                       // 68

    // zero degree array
    hipMemsetAsync(deg, 0, 1024 * sizeof(int), stream);
    // K1: mlp1 partials | edge degree | w2 gather
    k_fused1<<<nbMlp + nbDeg + nbW2g, 256, 0, stream>>>(
        dF, W1, h1p, nD, F, F / SK, gx, ei, deg, E, nD, oW2, oB2, sSes, W2p,
        B2p, nSe, S, nbMlp, nbDeg);
    // K2: mlp2 (reduce partials + layer 2) | scan
    k_fused2<<<nbMlp2 + 1, 256, 0, stream>>>(h1p, b1, W2, b2, xFd, nD, SK, deg,
                                             off, cursor, nbMlp2);
    // K3: bucket fill | M2 = [oW1; oB1] @ W2p
    k_fused3<<<nbFill + nbG16, 256, 0, stream>>>(ei, cursor, srcIdx, E, nD, oW1,
                                                 oB1, W2p, M2, nbFill);
    // K4: agg + sage fused (one block per drug)
    k_aggsage<<<nD, 128, 0, stream>>>(off, srcIdx, xFd, pE, sWl, sBl, sWr, fX,
                                      nD);
    // K5: PPc / QQc
    {
        dim3 g((nD + 15) / 16, 8);
        k_pq<<<g, 256, 0, stream>>>(fX, M2, B2p, PPc, QQc, nD);
    }
    // K6: final streaming epilogue
    k_final<<<(T + 1) / 2, 256, 0, stream>>>((const int2*)tpl, PPc, QQc,
                                             (float*)d_out, T, S);
}